// Round 5
// baseline (24.936 us; speedup 1.0000x reference)
//
#include <hip/hip_runtime.h>
#include <math.h>

#define BB 32
#define MM 256
#define H2 32
#define NOUT 8

// sinh(t) up to sign (caller squares it). Series keeps relative accuracy for
// small t; exp formula for |t| >= 0.5.
__device__ __forceinline__ float sinh_mag(float t) {
    float a  = fabsf(t);
    float e  = __expf(a);
    float big = 0.5f * (e - __builtin_amdgcn_rcpf(e));
    float t2 = t * t;
    float small = t + t * t2 * (1.0f/6.0f + t2 * (1.0f/120.0f));
    return (a < 0.5f) ? small : big;
}

// sin(t) up to sign (caller squares it). Series for small t avoids the
// cos-cancellation region; hw sin elsewhere.
__device__ __forceinline__ float sin_mag(float t) {
    float a  = fabsf(t);
    float t2 = t * t;
    float small = t + t * t2 * (-1.0f/6.0f + t2 * (1.0f/120.0f));
    float big = __sinf(t);
    return (a < 0.5f) ? small : big;
}

__global__ __launch_bounds__(256) void interaction_kernel(
    const float* __restrict__ x, const int* __restrict__ mask,
    const float* __restrict__ W1, const float* __restrict__ b1,
    const float* __restrict__ W2, const float* __restrict__ b2,
    float* __restrict__ out)
{
    __shared__ float o_lds[NOUT][MM];    // 8 KB: transpose buffer for stores

    // XCD-chunked swizzle: 8192 blocks, 8 XCDs -> contiguous 1024-block chunk
    // per XCD -> contiguous write region per XCD L2.
    const int bid = blockIdx.x;
    const int nb  = (bid & 7) * 1024 + (bid >> 3);
    const int b   = nb >> 8;
    const int i   = nb & 255;
    const int t   = threadIdx.x;
    const int w   = t >> 6;              // wave id 0..3
    const int l   = t & 63;              // lane

    // float4 view of this row: plane p's 1KB chunk = planes4*p + l
    float4* row4 = (float4*)(out + ((size_t)(b * NOUT)) * (MM * MM)
                                 + (size_t)i * MM);
    const int PS4 = MM * MM / 4;         // float4 plane stride

    const int mi = mask[b * MM + i];     // block-uniform
    if (mi == 0) {
        const float4 z4 = make_float4(0.f, 0.f, 0.f, 0.f);
        row4[(size_t)w       * PS4 + l] = z4;
        row4[(size_t)(w + 4) * PS4 + l] = z4;
        return;
    }

    // i-side (block-uniform -> scalar loads)
    const float eta_i = x[(b * MM + i) * 3 + 0];
    const float phi_i = x[(b * MM + i) * 3 + 1];
    const float lpt_i = x[(b * MM + i) * 3 + 2];

    // j-side per-thread (j == t)
    const float eta_j = x[(b * MM + t) * 3 + 0];
    const float phi_j = x[(b * MM + t) * 3 + 1];
    const float lpt_j = x[(b * MM + t) * 3 + 2];
    const float mf    = mask[b * MM + t] ? 1.f : 0.f;

    const float dx  = eta_i - eta_j;
    const float dy  = phi_i - phi_j;
    const float dr2 = dx * dx + dy * dy;

    const float L   = (dr2 > 0.f) ? 0.5f * __logf(dr2) : 0.f;
    const float fdr = L;
    const float fkt = (dr2 > 0.f) ? fminf(lpt_i, lpt_j) + L : 0.f;

    // cosh(dx) - cos(dy) = 2*(sinh^2(dx/2) + sin^2(dy/2))  (cancellation-free)
    const float sh = sinh_mag(0.5f * dx);
    const float sn = sin_mag(0.5f * dy);
    const float c  = 2.0f * (sh * sh + sn * sn);
    const float fmass = (c > 0.f) ? __logf(2.0f * c) + lpt_i + lpt_j : 0.f;

    float o[NOUT];
    #pragma unroll
    for (int p = 0; p < NOUT; ++p) o[p] = b2[p];

    #pragma unroll
    for (int k = 0; k < H2; ++k) {
        float z = b1[k];
        z = fmaf(fmass, W1[k * 3 + 0], z);
        z = fmaf(fdr,   W1[k * 3 + 1], z);
        z = fmaf(fkt,   W1[k * 3 + 2], z);
        z = (z >= 0.f) ? z : 0.01f * z;   // leaky_relu
        #pragma unroll
        for (int p = 0; p < NOUT; ++p)
            o[p] = fmaf(z, W2[p * H2 + k], o[p]);
    }

    // transpose through LDS: column write (2-way bank alias, free), then
    // 1KB-contiguous float4 stores per wave per plane
    #pragma unroll
    for (int p = 0; p < NOUT; ++p) o_lds[p][t] = o[p] * mf;
    __syncthreads();

    const float4 v0 = ((const float4*)o_lds[w    ])[l];
    const float4 v1 = ((const float4*)o_lds[w + 4])[l];
    row4[(size_t)w       * PS4 + l] = v0;
    row4[(size_t)(w + 4) * PS4 + l] = v1;
}

extern "C" void kernel_launch(void* const* d_in, const int* in_sizes, int n_in,
                              void* d_out, int out_size, void* d_ws, size_t ws_size,
                              hipStream_t stream) {
    const float* x    = (const float*)d_in[0];
    const int*   mask = (const int*)d_in[1];
    const float* W1   = (const float*)d_in[2];
    const float* b1   = (const float*)d_in[3];
    const float* W2   = (const float*)d_in[4];
    const float* b2   = (const float*)d_in[5];
    float* out = (float*)d_out;

    dim3 grid(BB * MM);
    dim3 block(MM);
    interaction_kernel<<<grid, block, 0, stream>>>(x, mask, W1, b1, W2, b2, out);
}